// Round 8
// baseline (217.071 us; speedup 1.0000x reference)
//
#include <hip/hip_runtime.h>
#include <hip/hip_bf16.h>

typedef __attribute__((ext_vector_type(8))) short short8;        // 8 bf16 MFMA A/B frag
typedef __attribute__((ext_vector_type(4))) float floatx4;       // MFMA C/D frag
typedef __attribute__((ext_vector_type(8))) unsigned short ushort8;

#define BTOT 65536
// ws byte offsets
#define WS_W1BF   0u          // 256 KB: [16 ks][16384B] frag/swizzle image of W1 bf16
#define WS_W2BF   262144u     // 128 KB: frag-ordered W2 bf16 (k-permuted to match h1 image)
#define WS_GBF    393216u     // 16 KB: B-frag image of G[q][k] (k-permuted to match h2 image)
#define WS_CONST  409600u     // 64 f32: [0..9]=Cb', [16]=tanh(cs), [32..59]=tanh(embs)
#define WS_PART   524288u     // 512 x 4 f32 partials

__device__ __forceinline__ unsigned short f2bf(float f) {
  unsigned u = __float_as_uint(f);
  unsigned r = u + 0x7FFFu + ((u >> 16) & 1u);   // RNE
  return (unsigned short)(r >> 16);
}

__device__ __forceinline__ unsigned cvtpk(float lo, float hi) {
  unsigned r;
  asm("v_cvt_pk_bf16_f32 %0, %1, %2" : "=v"(r) : "v"(lo), "v"(hi));
  return r;
}

__device__ __forceinline__ void gload16(const void* g, void* l) {
  __builtin_amdgcn_global_load_lds(
      (const __attribute__((address_space(1))) unsigned int*)g,
      (__attribute__((address_space(3))) unsigned int*)l, 16, 0, 0);
}

// ---------------------------------------------------------------------------
// K0: one-shot prep (unchanged — images verified by R6/R7 passes).
// ---------------------------------------------------------------------------
__global__ __launch_bounds__(256) void k0_prep(
    const float* __restrict__ w1, const float* __restrict__ w2,
    const float* __restrict__ ln_g, const float* __restrict__ ln_b,
    const float* __restrict__ sms, const float* __restrict__ smb,
    const float* __restrict__ embs, const float* __restrict__ cs,
    unsigned char* __restrict__ ws) {
  const int blk = blockIdx.x, tid = threadIdx.x;
  if (blk < 32) {               // W1 image: [ks][n 0..127][chunk c'], c = c'^(n&7)
    for (int g = blk * 256 + tid; g < 16384; g += 32 * 256) {
      int ks = g >> 10, d = g & 1023;
      int n = d >> 3, cp = d & 7, c = cp ^ (n & 7);
      ushort8 u;
      if (n < 120) {
        const float* s = w1 + n * 1024 + ks * 64 + c * 8;
        float4 v0 = *(const float4*)s, v1 = *(const float4*)(s + 4);
        u[0] = f2bf(v0.x); u[1] = f2bf(v0.y); u[2] = f2bf(v0.z); u[3] = f2bf(v0.w);
        u[4] = f2bf(v1.x); u[5] = f2bf(v1.y); u[6] = f2bf(v1.z); u[7] = f2bf(v1.w);
      } else {
#pragma unroll
        for (int j = 0; j < 8; ++j) u[j] = 0;
      }
      *(ushort8*)(ws + WS_W1BF + (unsigned)g * 16) = u;
    }
  } else if (blk < 40) {        // W2 frag image, k-permuted: kcol = (khat&7)*16 + (khat>>3)
    for (int g = (blk - 32) * 256 + tid; g < 8192; g += 8 * 256) {
      int lane = g & 63, f = g >> 6;
      int nt = f & 3, ks = (f >> 2) & 3, w = f >> 4;
      int n = w * 64 + nt * 16 + (lane & 15);
      ushort8 u;
#pragma unroll
      for (int j = 0; j < 8; ++j) {
        int khat = ks * 32 + (lane >> 4) * 8 + j;          // k-slot in h1 image
        int kcol = (khat & 7) * 16 + (khat >> 3);          // actual h1 column
        u[j] = (kcol < 120) ? f2bf(w2[n * 120 + kcol]) : (unsigned short)0;
      }
      *(ushort8*)(ws + WS_W2BF + (unsigned)g * 16) = u;
    }
  } else if (blk == 40) {       // G frag image, k-permuted to match h2 packed layout
    for (int e = tid; e < 1024; e += 256) {
      int t = e >> 6, lane = e & 63, q = lane & 15;
      ushort8 u;
#pragma unroll
      for (int j = 0; j < 8; ++j) {
        int khat = t * 32 + (lane >> 4) * 8 + j;           // k-slot in h2 image
        int col = (khat >> 6) * 64 + (khat & 3) * 16 + ((khat >> 2) & 15);
        float v = 0.f;
        if (q < 10) { int kk = q >> 1, c = q & 1; v = ln_g[col] * sms[kk * 1024 + col * 2 + c]; }
        u[j] = f2bf(v);
      }
      *(ushort8*)(ws + WS_GBF + (unsigned)e * 16) = u;
    }
  } else {                      // consts
    float* cst = (float*)(ws + WS_CONST);
    int lane = tid & 63, w = tid >> 6;
    for (int q = w; q < 10; q += 4) {
      int kk = q >> 1, c = q & 1;
      float s = 0.f;
#pragma unroll
      for (int i = 0; i < 8; ++i) { int k = lane + 64 * i; s += ln_b[k] * sms[kk * 1024 + k * 2 + c]; }
#pragma unroll
      for (int o = 32; o >= 1; o >>= 1) s += __shfl_xor(s, o);
      if (lane == 0) cst[q] = s + smb[kk * 2 + c];
    }
    if (tid == 0) cst[16] = tanhf(cs[0]);
    if (tid < 28) cst[32 + tid] = tanhf(embs[tid]);
  }
}

// ---------------------------------------------------------------------------
// KF: fully fused. 128 rows/block, grid 512, 8 waves, 2 blocks/CU (58.5KB LDS,
// launch_bounds(512,4) caps VGPR at 128).
// Phase 1 = R6's GEMM1 verbatim (direct-to-reg x, depth-2 prefetch, W1 dbuf
//   LDS, counted vmcnt(4)); epilogue packs h1 image into LDS [0,32K).
// Phase 2 = k2's pipeline on two 64-row halves, h1 from LDS (no HBM trip):
//   GEMM2 (W2 frags from L2 image) -> LN stats -> 4x 128-col h2n chunks
//   (16KB LDS) each followed by a GEMM3 partial -> CE tail, partials.
// LDS map: [0,32K) W1 dbuf -> h1 image | [32K,48K) h2 chunk |
//          [48K..58.5K) stats/musig/Af.
// ---------------------------------------------------------------------------
__global__ __launch_bounds__(512, 4) void kf_fused(
    const float* __restrict__ x, const unsigned char* __restrict__ w1bf,
    const float* __restrict__ b1, const unsigned char* __restrict__ w2f,
    const unsigned char* __restrict__ gbf, const float* __restrict__ cst,
    const float* __restrict__ b2, const int* __restrict__ labels,
    const int* __restrict__ domain, float* __restrict__ out,
    float* __restrict__ partials) {
  extern __shared__ unsigned char lds[];
  float* stats = (float*)(lds + 49152);      // [64][20] f32
  float* musig = (float*)(lds + 54272);      // [64][2]
  float* Af    = (float*)(lds + 54784);      // [64][20]

  const int tid = threadIdx.x, lane = tid & 63, w = tid >> 6;
  const int l15 = lane & 15, l4 = lane >> 4;

  // ================= phase 1: GEMM1 (R6 structure, verbatim) =================
  float b1v[8];
#pragma unroll
  for (int nt = 0; nt < 8; ++nt) {
    int col = nt * 16 + l15;
    b1v[nt] = b1[col < 120 ? col : 119];
  }
  __builtin_amdgcn_sched_barrier(0);

  const float* xbase = x + ((long)blockIdx.x * 128 + w * 16 + l15) * 1024 + l4 * 8;
  const unsigned char* wsrc = w1bf + w * 2048 + lane * 16;

  floatx4 acc1[8];
#pragma unroll
  for (int i = 0; i < 8; ++i) acc1[i] = floatx4{0.f, 0.f, 0.f, 0.f};

  float4 p[2][4];
  gload16(wsrc, lds + w * 2048);
  gload16(wsrc + 1024, lds + w * 2048 + 1024);
  __builtin_amdgcn_sched_barrier(0);
#pragma unroll
  for (int ss = 0; ss < 2; ++ss) {
    p[0][ss * 2]     = *(const float4*)(xbase + ss * 32);
    p[0][ss * 2 + 1] = *(const float4*)(xbase + ss * 32 + 4);
  }
#pragma unroll
  for (int ss = 0; ss < 2; ++ss) {
    p[1][ss * 2]     = *(const float4*)(xbase + 64 + ss * 32);
    p[1][ss * 2 + 1] = *(const float4*)(xbase + 64 + ss * 32 + 4);
  }
  __builtin_amdgcn_sched_barrier(0);
  asm volatile("s_waitcnt vmcnt(8)" ::: "memory");   // drain b1v + W(0); x stays in flight
  __builtin_amdgcn_s_barrier();

#pragma unroll
  for (int t = 0; t < 16; ++t) {
    const int cur = t & 1;
    short8 afr[2];
#pragma unroll
    for (int ss = 0; ss < 2; ++ss) {
      float4 a0 = p[cur][ss * 2], a1 = p[cur][ss * 2 + 1];
      union { unsigned u[4]; short8 s; } tmp;
      tmp.u[0] = cvtpk(a0.x, a0.y);
      tmp.u[1] = cvtpk(a0.z, a0.w);
      tmp.u[2] = cvtpk(a1.x, a1.y);
      tmp.u[3] = cvtpk(a1.z, a1.w);
      afr[ss] = tmp.s;
    }
    __builtin_amdgcn_sched_barrier(0);
    if (t < 15) {
      gload16(wsrc + (t + 1) * 16384, lds + (cur ^ 1) * 16384 + w * 2048);
      gload16(wsrc + (t + 1) * 16384 + 1024, lds + (cur ^ 1) * 16384 + w * 2048 + 1024);
    }
    __builtin_amdgcn_sched_barrier(0);
    if (t < 14) {
#pragma unroll
      for (int ss = 0; ss < 2; ++ss) {
        p[cur][ss * 2]     = *(const float4*)(xbase + (t + 2) * 64 + ss * 32);
        p[cur][ss * 2 + 1] = *(const float4*)(xbase + (t + 2) * 64 + ss * 32 + 4);
      }
    }
    __builtin_amdgcn_sched_barrier(0);
    const unsigned char* Wc = lds + cur * 16384;
#pragma unroll
    for (int ss = 0; ss < 2; ++ss)
#pragma unroll
      for (int nt = 0; nt < 8; ++nt) {
        int n = nt * 16 + l15;
        short8 b = *(const short8*)(Wc + n * 128 + ((ss * 64 + l4 * 16) ^ ((n & 7) << 4)));
        acc1[nt] = __builtin_amdgcn_mfma_f32_16x16x32_bf16(afr[ss], b, acc1[nt], 0, 0, 0);
      }
    if (t < 14)       asm volatile("s_waitcnt vmcnt(4) lgkmcnt(0)" ::: "memory");
    else if (t == 14) asm volatile("s_waitcnt vmcnt(0) lgkmcnt(0)" ::: "memory");
    else              asm volatile("s_waitcnt lgkmcnt(0)" ::: "memory");
    __builtin_amdgcn_s_barrier();
  }

  // epilogue: bias+relu -> k-permuted swizzled h1 image in LDS [0,32K)
#pragma unroll
  for (int r = 0; r < 4; ++r) {
    int row = w * 16 + l4 * 4 + r;
    float v[8];
#pragma unroll
    for (int nt = 0; nt < 8; ++nt) {
      float t0 = acc1[nt][r] + b1v[nt];
      v[nt] = t0 > 0.f ? t0 : 0.f;
    }
    if (l15 >= 8) v[7] = 0.f;                 // cols 120..127 -> 0
    union { unsigned u[4]; short8 s; } tmp;
    tmp.u[0] = cvtpk(v[0], v[1]);
    tmp.u[1] = cvtpk(v[2], v[3]);
    tmp.u[2] = cvtpk(v[4], v[5]);
    tmp.u[3] = cvtpk(v[6], v[7]);
    *(short8*)(lds + row * 256 + ((l15 * 16) ^ ((row & 7) << 4))) = tmp.s;
  }
  __syncthreads();

  // ================= phase 2: GEMM2 -> LN -> GEMM3 -> CE, two halves ==========
  const int n0 = w * 64;
  float b2v[4];
#pragma unroll
  for (int nt = 0; nt < 4; ++nt) b2v[nt] = b2[n0 + nt * 16 + l15];
  float wsumA = 0.f, scomA = 0.f, sspecA = 0.f;   // wave-0 lanes only

  for (int h = 0; h < 2; ++h) {
    // ---- GEMM2: A from h1 image (LDS), B frags from global W2 image
    floatx4 acc[4][4];
#pragma unroll
    for (int i = 0; i < 4; ++i)
#pragma unroll
      for (int j = 0; j < 4; ++j) acc[i][j] = floatx4{0.f, 0.f, 0.f, 0.f};
#pragma unroll
    for (int ks = 0; ks < 4; ++ks) {
      short8 a[4], b[4];
#pragma unroll
      for (int nt = 0; nt < 4; ++nt)
        b[nt] = *(const short8*)(w2f + (((w * 4 + ks) * 4 + nt) * 64 + lane) * 16);
#pragma unroll
      for (int mt = 0; mt < 4; ++mt) {
        int r = h * 64 + mt * 16 + l15;
        a[mt] = *(const short8*)(lds + r * 256 + ((ks * 64 + l4 * 16) ^ ((l15 & 7) << 4)));
      }
#pragma unroll
      for (int mt = 0; mt < 4; ++mt)
#pragma unroll
        for (int nt = 0; nt < 4; ++nt)
          acc[mt][nt] = __builtin_amdgcn_mfma_f32_16x16x32_bf16(a[mt], b[nt], acc[mt][nt], 0, 0, 0);
    }
    // ---- bias+relu; LN stats partials
#pragma unroll
    for (int mt = 0; mt < 4; ++mt)
#pragma unroll
      for (int nt = 0; nt < 4; ++nt)
#pragma unroll
        for (int r = 0; r < 4; ++r) {
          float v = acc[mt][nt][r] + b2v[nt];
          acc[mt][nt][r] = v > 0.f ? v : 0.f;
        }
#pragma unroll
    for (int mt = 0; mt < 4; ++mt)
#pragma unroll
      for (int r = 0; r < 4; ++r) {
        float s = 0.f, q2 = 0.f;
#pragma unroll
        for (int nt = 0; nt < 4; ++nt) { float v = acc[mt][nt][r]; s += v; q2 += v * v; }
#pragma unroll
        for (int o = 1; o <= 8; o <<= 1) { s += __shfl_xor(s, o); q2 += __shfl_xor(q2, o); }
        if (l15 == 0) {
          int rl = mt * 16 + l4 * 4 + r;
          stats[rl * 20 + w * 2] = s;
          stats[rl * 20 + w * 2 + 1] = q2;
        }
      }
    __syncthreads();
    if (tid < 64) {
      float S = 0.f, Q = 0.f;
#pragma unroll
      for (int j = 0; j < 8; ++j) { S += stats[tid * 20 + j * 2]; Q += stats[tid * 20 + j * 2 + 1]; }
      float mu = S * (1.f / 512.f);
      float var = Q * (1.f / 512.f) - mu * mu;
      musig[tid * 2] = mu;
      musig[tid * 2 + 1] = rsqrtf(var + 1e-5f);
    }
    __syncthreads();

    // ---- chunked h2n + GEMM3 (4 chunks x 128 cols)
    floatx4 a3 = floatx4{0.f, 0.f, 0.f, 0.f};
#pragma unroll
    for (int cc = 0; cc < 4; ++cc) {
      if ((w >> 1) == cc) {
#pragma unroll
        for (int mt = 0; mt < 4; ++mt)
#pragma unroll
          for (int r = 0; r < 4; ++r) {
            int rl = mt * 16 + l4 * 4 + r;
            float mu = musig[rl * 2], rs = musig[rl * 2 + 1];
            uint2 qq;
            qq.x = cvtpk((acc[mt][0][r] - mu) * rs, (acc[mt][1][r] - mu) * rs);
            qq.y = cvtpk((acc[mt][2][r] - mu) * rs, (acc[mt][3][r] - mu) * rs);
            *(uint2*)(lds + 32768 + rl * 256 +
                      (((w & 1) * 128 + l15 * 8) ^ ((rl & 7) << 4))) = qq;
          }
      }
      __syncthreads();
      if (w < 4) {
        int row = w * 16 + l15;
#pragma unroll
        for (int tl = 0; tl < 4; ++tl) {
          int t = cc * 4 + tl;
          short8 aa = *(const short8*)(lds + 32768 + row * 256 +
                                       ((tl * 64 + l4 * 16) ^ ((row & 7) << 4)));
          short8 bb = *(const short8*)(gbf + t * 1024 + lane * 16);
          a3 = __builtin_amdgcn_mfma_f32_16x16x32_bf16(aa, bb, a3, 0, 0, 0);
        }
      }
      __syncthreads();
    }
    if (w < 4) {
#pragma unroll
      for (int reg = 0; reg < 4; ++reg) {
        int orow = w * 16 + l4 * 4 + reg;
        if (l15 < 10) Af[orow * 20 + l15] = a3[reg];
      }
    }
    __syncthreads();

    // ---- CE tail for this half (wave 0)
    if (tid < 64) {
      long grow = (long)blockIdx.x * 128 + h * 64 + tid;
      float pd[10];
#pragma unroll
      for (int q = 0; q < 10; ++q) pd[q] = Af[tid * 20 + q] + cst[q];
      int lab = labels[grow], dm = domain[grow];
      float cw0 = cst[16];
      float ls0 = cw0 * pd[0], ls1 = cw0 * pd[1];
#pragma unroll
      for (int kk = 1; kk < 5; ++kk) {
        float c = cst[32 + dm * 4 + kk - 1];
        ls0 += c * pd[kk * 2];
        ls1 += c * pd[kk * 2 + 1];
      }
      float lc0 = pd[0], lc1 = pd[1];
      out[1 + grow * 2 + 0] = lc0;
      out[1 + grow * 2 + 1] = lc1;
      float m1 = fmaxf(lc0, lc1), nn1 = fminf(lc0, lc1);
      float lse1 = m1 + logf(1.f + expf(nn1 - m1));
      float nllc = lse1 - (lab ? lc1 : lc0);
      float m2 = fmaxf(ls0, ls1), nn2 = fminf(ls0, ls1);
      float lse2 = m2 + logf(1.f + expf(nn2 - m2));
      float nlls = lse2 - (lab ? ls1 : ls0);
      float wl = lab ? 0.9f : 0.1f;
      wsumA += wl;
      scomA += wl * nllc;
      sspecA += wl * nlls;
    }
    __syncthreads();   // protect stats/musig/Af/chunk before next half
  }

  if (tid < 64) {
#pragma unroll
    for (int o = 32; o >= 1; o >>= 1) {
      wsumA += __shfl_xor(wsumA, o);
      scomA += __shfl_xor(scomA, o);
      sspecA += __shfl_xor(sspecA, o);
    }
    if (tid == 0) {
      partials[(long)blockIdx.x * 4]     = wsumA;
      partials[(long)blockIdx.x * 4 + 1] = scomA;
      partials[(long)blockIdx.x * 4 + 2] = sspecA;
    }
  }
}

// ---------------------------------------------------------------------------
// K3: deterministic final reduce (512 partials) + orth loss + scalars.
// ---------------------------------------------------------------------------
__global__ __launch_bounds__(256) void k3_finalize(
    const float* __restrict__ partials, const float* __restrict__ sms,
    float* __restrict__ out) {
  __shared__ float wsums[4][3];
  __shared__ float ow[4];
  const int tid = threadIdx.x;
  const int lane = tid & 63, wid = tid >> 6;
  float sw = 0.f, sc = 0.f, ss = 0.f;
  for (int i = tid; i < 512; i += 256) {
    sw += partials[i * 4];
    sc += partials[i * 4 + 1];
    ss += partials[i * 4 + 2];
  }
#pragma unroll
  for (int o = 32; o >= 1; o >>= 1) {
    sw += __shfl_xor(sw, o);
    sc += __shfl_xor(sc, o);
    ss += __shfl_xor(ss, o);
  }
  if (lane == 0) { wsums[wid][0] = sw; wsums[wid][1] = sc; wsums[wid][2] = ss; }

  float osum = 0.f;
  for (int p = wid; p < 50; p += 4) {
    int c = p / 25, kk = (p / 5) % 5, j = p % 5;
    float acc = 0.f;
#pragma unroll
    for (int hh = 0; hh < 8; ++hh) {
      int h = lane + 64 * hh;
      acc += sms[kk * 1024 + h * 2 + c] * sms[j * 1024 + h * 2 + c];
    }
#pragma unroll
    for (int o = 32; o >= 1; o >>= 1) acc += __shfl_xor(acc, o);
    float d = acc - ((kk == j) ? 1.f : 0.f);
    osum += d * d;
  }
  if (lane == 0) ow[wid] = osum;
  __syncthreads();
  if (tid == 0) {
    float SW = 0.f, SC = 0.f, SS = 0.f, OS = 0.f;
    for (int w = 0; w < 4; ++w) {
      SW += wsums[w][0]; SC += wsums[w][1]; SS += wsums[w][2]; OS += ow[w];
    }
    float orth = OS * (1.f / 50.f);
    float cls = SC / SW;
    float spec = SS / SW;
    out[0] = cls + spec + orth;
    out[131073] = cls;
    out[131074] = spec;
    out[131075] = orth;
  }
}

extern "C" void kernel_launch(void* const* d_in, const int* in_sizes, int n_in,
                              void* d_out, int out_size, void* d_ws, size_t ws_size,
                              hipStream_t stream) {
  const float* x      = (const float*)d_in[0];
  const int* labels   = (const int*)d_in[1];
  const int* domain   = (const int*)d_in[2];
  const float* fc1_w  = (const float*)d_in[3];
  const float* fc1_b  = (const float*)d_in[4];
  const float* fc2_w  = (const float*)d_in[5];
  const float* fc2_b  = (const float*)d_in[6];
  const float* ln_g   = (const float*)d_in[7];
  const float* ln_b   = (const float*)d_in[8];
  const float* sms    = (const float*)d_in[9];
  const float* sm_b   = (const float*)d_in[10];
  const float* embs   = (const float*)d_in[11];
  const float* cs_wt  = (const float*)d_in[12];
  float* out = (float*)d_out;
  unsigned char* ws = (unsigned char*)d_ws;

  (void)hipFuncSetAttribute((const void*)kf_fused,
                            hipFuncAttributeMaxDynamicSharedMemorySize, 59904);

  hipLaunchKernelGGL(k0_prep, dim3(42), dim3(256), 0, stream,
                     fc1_w, fc2_w, ln_g, ln_b, sms, sm_b, embs, cs_wt, ws);
  hipLaunchKernelGGL(kf_fused, dim3(BTOT / 128), dim3(512), 59904, stream,
                     x, ws + WS_W1BF, fc1_b, ws + WS_W2BF, ws + WS_GBF,
                     (const float*)(ws + WS_CONST), fc2_b,
                     labels, domain, out, (float*)(ws + WS_PART));
  hipLaunchKernelGGL(k3_finalize, dim3(1), dim3(256), 0, stream,
                     (const float*)(ws + WS_PART), sms, out);
}

// Round 9
// 123.735 us; speedup vs baseline: 1.7543x; 1.7543x over previous
//
#include <hip/hip_runtime.h>
#include <hip/hip_bf16.h>

typedef __attribute__((ext_vector_type(8))) short short8;        // 8 bf16 MFMA A/B frag
typedef __attribute__((ext_vector_type(4))) float floatx4;       // MFMA C/D frag
typedef __attribute__((ext_vector_type(8))) unsigned short ushort8;

#define BTOT 65536
// ws byte offsets
#define WS_W1BF   0u          // 256 KB: [16 ks][16384B] frag/swizzle image of W1 bf16
#define WS_W2BF   262144u     // 128 KB: frag-ordered W2 bf16 (k-permuted to match h1 image)
#define WS_GBF    393216u     // 16 KB: B-frag image of G[q][k] (k-permuted to match h2 image)
#define WS_CONST  409600u     // 64 f32: [0..9]=Cb', [16]=tanh(cs), [32..59]=tanh(embs)
#define WS_PART   524288u     // 512 x 4 f32 partials

__device__ __forceinline__ unsigned short f2bf(float f) {
  unsigned u = __float_as_uint(f);
  unsigned r = u + 0x7FFFu + ((u >> 16) & 1u);   // RNE
  return (unsigned short)(r >> 16);
}

__device__ __forceinline__ unsigned cvtpk(float lo, float hi) {
  unsigned r;
  asm("v_cvt_pk_bf16_f32 %0, %1, %2" : "=v"(r) : "v"(lo), "v"(hi));
  return r;
}

__device__ __forceinline__ void gload16(const void* g, void* l) {
  __builtin_amdgcn_global_load_lds(
      (const __attribute__((address_space(1))) unsigned int*)g,
      (__attribute__((address_space(3))) unsigned int*)l, 16, 0, 0);
}

// ---------------------------------------------------------------------------
// K0: one-shot prep (unchanged — images verified by R6/R7/R8 passes).
// ---------------------------------------------------------------------------
__global__ __launch_bounds__(256) void k0_prep(
    const float* __restrict__ w1, const float* __restrict__ w2,
    const float* __restrict__ ln_g, const float* __restrict__ ln_b,
    const float* __restrict__ sms, const float* __restrict__ smb,
    const float* __restrict__ embs, const float* __restrict__ cs,
    unsigned char* __restrict__ ws) {
  const int blk = blockIdx.x, tid = threadIdx.x;
  if (blk < 32) {               // W1 image: [ks][n 0..127][chunk c'], c = c'^(n&7)
    for (int g = blk * 256 + tid; g < 16384; g += 32 * 256) {
      int ks = g >> 10, d = g & 1023;
      int n = d >> 3, cp = d & 7, c = cp ^ (n & 7);
      ushort8 u;
      if (n < 120) {
        const float* s = w1 + n * 1024 + ks * 64 + c * 8;
        float4 v0 = *(const float4*)s, v1 = *(const float4*)(s + 4);
        u[0] = f2bf(v0.x); u[1] = f2bf(v0.y); u[2] = f2bf(v0.z); u[3] = f2bf(v0.w);
        u[4] = f2bf(v1.x); u[5] = f2bf(v1.y); u[6] = f2bf(v1.z); u[7] = f2bf(v1.w);
      } else {
#pragma unroll
        for (int j = 0; j < 8; ++j) u[j] = 0;
      }
      *(ushort8*)(ws + WS_W1BF + (unsigned)g * 16) = u;
    }
  } else if (blk < 40) {        // W2 frag image, k-permuted: kcol = (khat&7)*16 + (khat>>3)
    for (int g = (blk - 32) * 256 + tid; g < 8192; g += 8 * 256) {
      int lane = g & 63, f = g >> 6;
      int nt = f & 3, ks = (f >> 2) & 3, w = f >> 4;
      int n = w * 64 + nt * 16 + (lane & 15);
      ushort8 u;
#pragma unroll
      for (int j = 0; j < 8; ++j) {
        int khat = ks * 32 + (lane >> 4) * 8 + j;          // k-slot in h1 image
        int kcol = (khat & 7) * 16 + (khat >> 3);          // actual h1 column
        u[j] = (kcol < 120) ? f2bf(w2[n * 120 + kcol]) : (unsigned short)0;
      }
      *(ushort8*)(ws + WS_W2BF + (unsigned)g * 16) = u;
    }
  } else if (blk == 40) {       // G frag image, k-permuted to match h2 packed layout
    for (int e = tid; e < 1024; e += 256) {
      int t = e >> 6, lane = e & 63, q = lane & 15;
      ushort8 u;
#pragma unroll
      for (int j = 0; j < 8; ++j) {
        int khat = t * 32 + (lane >> 4) * 8 + j;           // k-slot in h2 image
        int col = (khat >> 6) * 64 + (khat & 3) * 16 + ((khat >> 2) & 15);
        float v = 0.f;
        if (q < 10) { int kk = q >> 1, c = q & 1; v = ln_g[col] * sms[kk * 1024 + col * 2 + c]; }
        u[j] = f2bf(v);
      }
      *(ushort8*)(ws + WS_GBF + (unsigned)e * 16) = u;
    }
  } else {                      // consts
    float* cst = (float*)(ws + WS_CONST);
    int lane = tid & 63, w = tid >> 6;
    for (int q = w; q < 10; q += 4) {
      int kk = q >> 1, c = q & 1;
      float s = 0.f;
#pragma unroll
      for (int i = 0; i < 8; ++i) { int k = lane + 64 * i; s += ln_b[k] * sms[kk * 1024 + k * 2 + c]; }
#pragma unroll
      for (int o = 32; o >= 1; o >>= 1) s += __shfl_xor(s, o);
      if (lane == 0) cst[q] = s + smb[kk * 2 + c];
    }
    if (tid == 0) cst[16] = tanhf(cs[0]);
    if (tid < 28) cst[32 + tid] = tanhf(embs[tid]);
  }
}

// ---------------------------------------------------------------------------
// KF: fully fused, identical to R8 EXCEPT __launch_bounds__(512, 2):
// the 2nd arg is min BLOCKS/CU (CUDA semantics, confirmed by R8's VGPR=64 at
// (512,4) = 4 blocks = 8 waves/SIMD = 64-reg cap + 161MB spill writes).
// (512,2) -> 2 blocks/CU -> 4 waves/SIMD -> 128-reg cap: phase-1 (~100) and
// phase-2 (~115) both fit spill-free; LDS 58.5KB also gives 2 blocks/CU.
// ---------------------------------------------------------------------------
__global__ __launch_bounds__(512, 2) void kf_fused(
    const float* __restrict__ x, const unsigned char* __restrict__ w1bf,
    const float* __restrict__ b1, const unsigned char* __restrict__ w2f,
    const unsigned char* __restrict__ gbf, const float* __restrict__ cst,
    const float* __restrict__ b2, const int* __restrict__ labels,
    const int* __restrict__ domain, float* __restrict__ out,
    float* __restrict__ partials) {
  extern __shared__ unsigned char lds[];
  float* stats = (float*)(lds + 49152);      // [64][20] f32
  float* musig = (float*)(lds + 54272);      // [64][2]
  float* Af    = (float*)(lds + 54784);      // [64][20]

  const int tid = threadIdx.x, lane = tid & 63, w = tid >> 6;
  const int l15 = lane & 15, l4 = lane >> 4;

  // ================= phase 1: GEMM1 (R6 structure) =================
  float b1v[8];
#pragma unroll
  for (int nt = 0; nt < 8; ++nt) {
    int col = nt * 16 + l15;
    b1v[nt] = b1[col < 120 ? col : 119];
  }
  __builtin_amdgcn_sched_barrier(0);

  const float* xbase = x + ((long)blockIdx.x * 128 + w * 16 + l15) * 1024 + l4 * 8;
  const unsigned char* wsrc = w1bf + w * 2048 + lane * 16;

  floatx4 acc1[8];
#pragma unroll
  for (int i = 0; i < 8; ++i) acc1[i] = floatx4{0.f, 0.f, 0.f, 0.f};

  float4 p[2][4];
  gload16(wsrc, lds + w * 2048);
  gload16(wsrc + 1024, lds + w * 2048 + 1024);
  __builtin_amdgcn_sched_barrier(0);
#pragma unroll
  for (int ss = 0; ss < 2; ++ss) {
    p[0][ss * 2]     = *(const float4*)(xbase + ss * 32);
    p[0][ss * 2 + 1] = *(const float4*)(xbase + ss * 32 + 4);
  }
#pragma unroll
  for (int ss = 0; ss < 2; ++ss) {
    p[1][ss * 2]     = *(const float4*)(xbase + 64 + ss * 32);
    p[1][ss * 2 + 1] = *(const float4*)(xbase + 64 + ss * 32 + 4);
  }
  __builtin_amdgcn_sched_barrier(0);
  asm volatile("s_waitcnt vmcnt(8)" ::: "memory");   // drain b1v + W(0); x stays in flight
  __builtin_amdgcn_s_barrier();

#pragma unroll
  for (int t = 0; t < 16; ++t) {
    const int cur = t & 1;
    short8 afr[2];
#pragma unroll
    for (int ss = 0; ss < 2; ++ss) {
      float4 a0 = p[cur][ss * 2], a1 = p[cur][ss * 2 + 1];
      union { unsigned u[4]; short8 s; } tmp;
      tmp.u[0] = cvtpk(a0.x, a0.y);
      tmp.u[1] = cvtpk(a0.z, a0.w);
      tmp.u[2] = cvtpk(a1.x, a1.y);
      tmp.u[3] = cvtpk(a1.z, a1.w);
      afr[ss] = tmp.s;
    }
    __builtin_amdgcn_sched_barrier(0);
    if (t < 15) {
      gload16(wsrc + (t + 1) * 16384, lds + (cur ^ 1) * 16384 + w * 2048);
      gload16(wsrc + (t + 1) * 16384 + 1024, lds + (cur ^ 1) * 16384 + w * 2048 + 1024);
    }
    __builtin_amdgcn_sched_barrier(0);
    if (t < 14) {
#pragma unroll
      for (int ss = 0; ss < 2; ++ss) {
        p[cur][ss * 2]     = *(const float4*)(xbase + (t + 2) * 64 + ss * 32);
        p[cur][ss * 2 + 1] = *(const float4*)(xbase + (t + 2) * 64 + ss * 32 + 4);
      }
    }
    __builtin_amdgcn_sched_barrier(0);
    const unsigned char* Wc = lds + cur * 16384;
#pragma unroll
    for (int ss = 0; ss < 2; ++ss)
#pragma unroll
      for (int nt = 0; nt < 8; ++nt) {
        int n = nt * 16 + l15;
        short8 b = *(const short8*)(Wc + n * 128 + ((ss * 64 + l4 * 16) ^ ((n & 7) << 4)));
        acc1[nt] = __builtin_amdgcn_mfma_f32_16x16x32_bf16(afr[ss], b, acc1[nt], 0, 0, 0);
      }
    if (t < 14)       asm volatile("s_waitcnt vmcnt(4) lgkmcnt(0)" ::: "memory");
    else if (t == 14) asm volatile("s_waitcnt vmcnt(0) lgkmcnt(0)" ::: "memory");
    else              asm volatile("s_waitcnt lgkmcnt(0)" ::: "memory");
    __builtin_amdgcn_s_barrier();
  }

  // epilogue: bias+relu -> k-permuted swizzled h1 image in LDS [0,32K)
#pragma unroll
  for (int r = 0; r < 4; ++r) {
    int row = w * 16 + l4 * 4 + r;
    float v[8];
#pragma unroll
    for (int nt = 0; nt < 8; ++nt) {
      float t0 = acc1[nt][r] + b1v[nt];
      v[nt] = t0 > 0.f ? t0 : 0.f;
    }
    if (l15 >= 8) v[7] = 0.f;                 // cols 120..127 -> 0
    union { unsigned u[4]; short8 s; } tmp;
    tmp.u[0] = cvtpk(v[0], v[1]);
    tmp.u[1] = cvtpk(v[2], v[3]);
    tmp.u[2] = cvtpk(v[4], v[5]);
    tmp.u[3] = cvtpk(v[6], v[7]);
    *(short8*)(lds + row * 256 + ((l15 * 16) ^ ((row & 7) << 4))) = tmp.s;
  }
  __syncthreads();

  // ================= phase 2: GEMM2 -> LN -> GEMM3 -> CE, two halves ==========
  const int n0 = w * 64;
  float b2v[4];
#pragma unroll
  for (int nt = 0; nt < 4; ++nt) b2v[nt] = b2[n0 + nt * 16 + l15];
  float wsumA = 0.f, scomA = 0.f, sspecA = 0.f;   // wave-0 lanes only

  for (int h = 0; h < 2; ++h) {
    // ---- GEMM2: A from h1 image (LDS), B frags from global W2 image
    floatx4 acc[4][4];
#pragma unroll
    for (int i = 0; i < 4; ++i)
#pragma unroll
      for (int j = 0; j < 4; ++j) acc[i][j] = floatx4{0.f, 0.f, 0.f, 0.f};
#pragma unroll
    for (int ks = 0; ks < 4; ++ks) {
      short8 a[4], b[4];
#pragma unroll
      for (int nt = 0; nt < 4; ++nt)
        b[nt] = *(const short8*)(w2f + (((w * 4 + ks) * 4 + nt) * 64 + lane) * 16);
#pragma unroll
      for (int mt = 0; mt < 4; ++mt) {
        int r = h * 64 + mt * 16 + l15;
        a[mt] = *(const short8*)(lds + r * 256 + ((ks * 64 + l4 * 16) ^ ((l15 & 7) << 4)));
      }
#pragma unroll
      for (int mt = 0; mt < 4; ++mt)
#pragma unroll
        for (int nt = 0; nt < 4; ++nt)
          acc[mt][nt] = __builtin_amdgcn_mfma_f32_16x16x32_bf16(a[mt], b[nt], acc[mt][nt], 0, 0, 0);
    }
    // ---- bias+relu; LN stats partials
#pragma unroll
    for (int mt = 0; mt < 4; ++mt)
#pragma unroll
      for (int nt = 0; nt < 4; ++nt)
#pragma unroll
        for (int r = 0; r < 4; ++r) {
          float v = acc[mt][nt][r] + b2v[nt];
          acc[mt][nt][r] = v > 0.f ? v : 0.f;
        }
#pragma unroll
    for (int mt = 0; mt < 4; ++mt)
#pragma unroll
      for (int r = 0; r < 4; ++r) {
        float s = 0.f, q2 = 0.f;
#pragma unroll
        for (int nt = 0; nt < 4; ++nt) { float v = acc[mt][nt][r]; s += v; q2 += v * v; }
#pragma unroll
        for (int o = 1; o <= 8; o <<= 1) { s += __shfl_xor(s, o); q2 += __shfl_xor(q2, o); }
        if (l15 == 0) {
          int rl = mt * 16 + l4 * 4 + r;
          stats[rl * 20 + w * 2] = s;
          stats[rl * 20 + w * 2 + 1] = q2;
        }
      }
    __syncthreads();
    if (tid < 64) {
      float S = 0.f, Q = 0.f;
#pragma unroll
      for (int j = 0; j < 8; ++j) { S += stats[tid * 20 + j * 2]; Q += stats[tid * 20 + j * 2 + 1]; }
      float mu = S * (1.f / 512.f);
      float var = Q * (1.f / 512.f) - mu * mu;
      musig[tid * 2] = mu;
      musig[tid * 2 + 1] = rsqrtf(var + 1e-5f);
    }
    __syncthreads();

    // ---- chunked h2n + GEMM3 (4 chunks x 128 cols)
    floatx4 a3 = floatx4{0.f, 0.f, 0.f, 0.f};
#pragma unroll
    for (int cc = 0; cc < 4; ++cc) {
      if ((w >> 1) == cc) {
#pragma unroll
        for (int mt = 0; mt < 4; ++mt)
#pragma unroll
          for (int r = 0; r < 4; ++r) {
            int rl = mt * 16 + l4 * 4 + r;
            float mu = musig[rl * 2], rs = musig[rl * 2 + 1];
            uint2 qq;
            qq.x = cvtpk((acc[mt][0][r] - mu) * rs, (acc[mt][1][r] - mu) * rs);
            qq.y = cvtpk((acc[mt][2][r] - mu) * rs, (acc[mt][3][r] - mu) * rs);
            *(uint2*)(lds + 32768 + rl * 256 +
                      (((w & 1) * 128 + l15 * 8) ^ ((rl & 7) << 4))) = qq;
          }
      }
      __syncthreads();
      if (w < 4) {
        int row = w * 16 + l15;
#pragma unroll
        for (int tl = 0; tl < 4; ++tl) {
          int t = cc * 4 + tl;
          short8 aa = *(const short8*)(lds + 32768 + row * 256 +
                                       ((tl * 64 + l4 * 16) ^ ((row & 7) << 4)));
          short8 bb = *(const short8*)(gbf + t * 1024 + lane * 16);
          a3 = __builtin_amdgcn_mfma_f32_16x16x32_bf16(aa, bb, a3, 0, 0, 0);
        }
      }
      __syncthreads();
    }
    if (w < 4) {
#pragma unroll
      for (int reg = 0; reg < 4; ++reg) {
        int orow = w * 16 + l4 * 4 + reg;
        if (l15 < 10) Af[orow * 20 + l15] = a3[reg];
      }
    }
    __syncthreads();

    // ---- CE tail for this half (wave 0)
    if (tid < 64) {
      long grow = (long)blockIdx.x * 128 + h * 64 + tid;
      float pd[10];
#pragma unroll
      for (int q = 0; q < 10; ++q) pd[q] = Af[tid * 20 + q] + cst[q];
      int lab = labels[grow], dm = domain[grow];
      float cw0 = cst[16];
      float ls0 = cw0 * pd[0], ls1 = cw0 * pd[1];
#pragma unroll
      for (int kk = 1; kk < 5; ++kk) {
        float c = cst[32 + dm * 4 + kk - 1];
        ls0 += c * pd[kk * 2];
        ls1 += c * pd[kk * 2 + 1];
      }
      float lc0 = pd[0], lc1 = pd[1];
      out[1 + grow * 2 + 0] = lc0;
      out[1 + grow * 2 + 1] = lc1;
      float m1 = fmaxf(lc0, lc1), nn1 = fminf(lc0, lc1);
      float lse1 = m1 + logf(1.f + expf(nn1 - m1));
      float nllc = lse1 - (lab ? lc1 : lc0);
      float m2 = fmaxf(ls0, ls1), nn2 = fminf(ls0, ls1);
      float lse2 = m2 + logf(1.f + expf(nn2 - m2));
      float nlls = lse2 - (lab ? ls1 : ls0);
      float wl = lab ? 0.9f : 0.1f;
      wsumA += wl;
      scomA += wl * nllc;
      sspecA += wl * nlls;
    }
    __syncthreads();   // protect stats/musig/Af/chunk before next half
  }

  if (tid < 64) {
#pragma unroll
    for (int o = 32; o >= 1; o >>= 1) {
      wsumA += __shfl_xor(wsumA, o);
      scomA += __shfl_xor(scomA, o);
      sspecA += __shfl_xor(sspecA, o);
    }
    if (tid == 0) {
      partials[(long)blockIdx.x * 4]     = wsumA;
      partials[(long)blockIdx.x * 4 + 1] = scomA;
      partials[(long)blockIdx.x * 4 + 2] = sspecA;
    }
  }
}

// ---------------------------------------------------------------------------
// K3: deterministic final reduce (512 partials) + orth loss + scalars.
// ---------------------------------------------------------------------------
__global__ __launch_bounds__(256) void k3_finalize(
    const float* __restrict__ partials, const float* __restrict__ sms,
    float* __restrict__ out) {
  __shared__ float wsums[4][3];
  __shared__ float ow[4];
  const int tid = threadIdx.x;
  const int lane = tid & 63, wid = tid >> 6;
  float sw = 0.f, sc = 0.f, ss = 0.f;
  for (int i = tid; i < 512; i += 256) {
    sw += partials[i * 4];
    sc += partials[i * 4 + 1];
    ss += partials[i * 4 + 2];
  }
#pragma unroll
  for (int o = 32; o >= 1; o >>= 1) {
    sw += __shfl_xor(sw, o);
    sc += __shfl_xor(sc, o);
    ss += __shfl_xor(ss, o);
  }
  if (lane == 0) { wsums[wid][0] = sw; wsums[wid][1] = sc; wsums[wid][2] = ss; }

  float osum = 0.f;
  for (int p = wid; p < 50; p += 4) {
    int c = p / 25, kk = (p / 5) % 5, j = p % 5;
    float acc = 0.f;
#pragma unroll
    for (int hh = 0; hh < 8; ++hh) {
      int h = lane + 64 * hh;
      acc += sms[kk * 1024 + h * 2 + c] * sms[j * 1024 + h * 2 + c];
    }
#pragma unroll
    for (int o = 32; o >= 1; o >>= 1) acc += __shfl_xor(acc, o);
    float d = acc - ((kk == j) ? 1.f : 0.f);
    osum += d * d;
  }
  if (lane == 0) ow[wid] = osum;
  __syncthreads();
  if (tid == 0) {
    float SW = 0.f, SC = 0.f, SS = 0.f, OS = 0.f;
    for (int w = 0; w < 4; ++w) {
      SW += wsums[w][0]; SC += wsums[w][1]; SS += wsums[w][2]; OS += ow[w];
    }
    float orth = OS * (1.f / 50.f);
    float cls = SC / SW;
    float spec = SS / SW;
    out[0] = cls + spec + orth;
    out[131073] = cls;
    out[131074] = spec;
    out[131075] = orth;
  }
}

extern "C" void kernel_launch(void* const* d_in, const int* in_sizes, int n_in,
                              void* d_out, int out_size, void* d_ws, size_t ws_size,
                              hipStream_t stream) {
  const float* x      = (const float*)d_in[0];
  const int* labels   = (const int*)d_in[1];
  const int* domain   = (const int*)d_in[2];
  const float* fc1_w  = (const float*)d_in[3];
  const float* fc1_b  = (const float*)d_in[4];
  const float* fc2_w  = (const float*)d_in[5];
  const float* fc2_b  = (const float*)d_in[6];
  const float* ln_g   = (const float*)d_in[7];
  const float* ln_b   = (const float*)d_in[8];
  const float* sms    = (const float*)d_in[9];
  const float* sm_b   = (const float*)d_in[10];
  const float* embs   = (const float*)d_in[11];
  const float* cs_wt  = (const float*)d_in[12];
  float* out = (float*)d_out;
  unsigned char* ws = (unsigned char*)d_ws;

  (void)hipFuncSetAttribute((const void*)kf_fused,
                            hipFuncAttributeMaxDynamicSharedMemorySize, 59904);

  hipLaunchKernelGGL(k0_prep, dim3(42), dim3(256), 0, stream,
                     fc1_w, fc2_w, ln_g, ln_b, sms, sm_b, embs, cs_wt, ws);
  hipLaunchKernelGGL(kf_fused, dim3(BTOT / 128), dim3(512), 59904, stream,
                     x, ws + WS_W1BF, fc1_b, ws + WS_W2BF, ws + WS_GBF,
                     (const float*)(ws + WS_CONST), fc2_b,
                     labels, domain, out, (float*)(ws + WS_PART));
  hipLaunchKernelGGL(k3_finalize, dim3(1), dim3(256), 0, stream,
                     (const float*)(ws + WS_PART), sms, out);
}

// Round 10
// 104.759 us; speedup vs baseline: 2.0721x; 1.1811x over previous
//
#include <hip/hip_runtime.h>
#include <hip/hip_bf16.h>

typedef __attribute__((ext_vector_type(8))) short short8;        // 8 bf16 MFMA A/B frag
typedef __attribute__((ext_vector_type(4))) float floatx4;       // MFMA C/D frag
typedef __attribute__((ext_vector_type(8))) unsigned short ushort8;

#define BTOT 65536
// ws byte offsets
#define WS_W1BF   0u          // 256 KB: [16 ks][16384B] frag/swizzle image of W1 bf16
#define WS_W2BF   262144u     // 128 KB: frag-ordered W2 bf16 (k-permuted to match h1 image)
#define WS_GBF    393216u     // 16 KB: B-frag image of G[q][k] (k-permuted to match h2 image)
#define WS_CONST  409600u     // 64 f32: [0..9]=Cb', [16]=tanh(cs), [32..59]=tanh(embs)
#define WS_H1BF   524288u     // 16 MB: 512 k1-blocks x 32768B k-permuted swizzled h1 bf16
#define WS_PART   17301504u   // 1024 x 4 f32 partials

__device__ __forceinline__ unsigned short f2bf(float f) {
  unsigned u = __float_as_uint(f);
  unsigned r = u + 0x7FFFu + ((u >> 16) & 1u);   // RNE
  return (unsigned short)(r >> 16);
}

__device__ __forceinline__ unsigned cvtpk(float lo, float hi) {
  unsigned r;
  asm("v_cvt_pk_bf16_f32 %0, %1, %2" : "=v"(r) : "v"(lo), "v"(hi));
  return r;
}

__device__ __forceinline__ void gload16(const void* g, void* l) {
  __builtin_amdgcn_global_load_lds(
      (const __attribute__((address_space(1))) unsigned int*)g,
      (__attribute__((address_space(3))) unsigned int*)l, 16, 0, 0);
}

// ---------------------------------------------------------------------------
// K0: one-shot prep (unchanged — images verified by R6/R8/R9 passes).
// ---------------------------------------------------------------------------
__global__ __launch_bounds__(256) void k0_prep(
    const float* __restrict__ w1, const float* __restrict__ w2,
    const float* __restrict__ ln_g, const float* __restrict__ ln_b,
    const float* __restrict__ sms, const float* __restrict__ smb,
    const float* __restrict__ embs, const float* __restrict__ cs,
    unsigned char* __restrict__ ws) {
  const int blk = blockIdx.x, tid = threadIdx.x;
  if (blk < 32) {               // W1 image: [ks][n 0..127][chunk c'], c = c'^(n&7)
    for (int g = blk * 256 + tid; g < 16384; g += 32 * 256) {
      int ks = g >> 10, d = g & 1023;
      int n = d >> 3, cp = d & 7, c = cp ^ (n & 7);
      ushort8 u;
      if (n < 120) {
        const float* s = w1 + n * 1024 + ks * 64 + c * 8;
        float4 v0 = *(const float4*)s, v1 = *(const float4*)(s + 4);
        u[0] = f2bf(v0.x); u[1] = f2bf(v0.y); u[2] = f2bf(v0.z); u[3] = f2bf(v0.w);
        u[4] = f2bf(v1.x); u[5] = f2bf(v1.y); u[6] = f2bf(v1.z); u[7] = f2bf(v1.w);
      } else {
#pragma unroll
        for (int j = 0; j < 8; ++j) u[j] = 0;
      }
      *(ushort8*)(ws + WS_W1BF + (unsigned)g * 16) = u;
    }
  } else if (blk < 40) {        // W2 frag image, k-permuted: kcol = (khat&7)*16 + (khat>>3)
    for (int g = (blk - 32) * 256 + tid; g < 8192; g += 8 * 256) {
      int lane = g & 63, f = g >> 6;
      int nt = f & 3, ks = (f >> 2) & 3, w = f >> 4;
      int n = w * 64 + nt * 16 + (lane & 15);
      ushort8 u;
#pragma unroll
      for (int j = 0; j < 8; ++j) {
        int khat = ks * 32 + (lane >> 4) * 8 + j;          // k-slot in h1 image
        int kcol = (khat & 7) * 16 + (khat >> 3);          // actual h1 column
        u[j] = (kcol < 120) ? f2bf(w2[n * 120 + kcol]) : (unsigned short)0;
      }
      *(ushort8*)(ws + WS_W2BF + (unsigned)g * 16) = u;
    }
  } else if (blk == 40) {       // G frag image, k-permuted to match h2 packed layout
    for (int e = tid; e < 1024; e += 256) {
      int t = e >> 6, lane = e & 63, q = lane & 15;
      ushort8 u;
#pragma unroll
      for (int j = 0; j < 8; ++j) {
        int khat = t * 32 + (lane >> 4) * 8 + j;           // k-slot in h2 image
        int col = (khat >> 6) * 64 + (khat & 3) * 16 + ((khat >> 2) & 15);
        float v = 0.f;
        if (q < 10) { int kk = q >> 1, c = q & 1; v = ln_g[col] * sms[kk * 1024 + col * 2 + c]; }
        u[j] = f2bf(v);
      }
      *(ushort8*)(ws + WS_GBF + (unsigned)e * 16) = u;
    }
  } else {                      // consts
    float* cst = (float*)(ws + WS_CONST);
    int lane = tid & 63, w = tid >> 6;
    for (int q = w; q < 10; q += 4) {
      int kk = q >> 1, c = q & 1;
      float s = 0.f;
#pragma unroll
      for (int i = 0; i < 8; ++i) { int k = lane + 64 * i; s += ln_b[k] * sms[kk * 1024 + k * 2 + c]; }
#pragma unroll
      for (int o = 32; o >= 1; o >>= 1) s += __shfl_xor(s, o);
      if (lane == 0) cst[q] = s + smb[kk * 2 + c];
    }
    if (tid == 0) cst[16] = tanhf(cs[0]);
    if (tid < 28) cst[32 + tid] = tanhf(embs[tid]);
  }
}

// ---------------------------------------------------------------------------
// K1: h1 = relu(x @ W1^T + b1). R6 structure, launch_bounds(512, 2):
// 2 BLOCKS/CU (CUDA semantics, confirmed R8/R9: VGPR cap 64@4 / 128@2) ->
// 128-reg cap; usage ~70 VGPR + 32 AGPR = spill-free (R5-R8 ran this loop
// with a 64-reg cap and ~40 regs/lane spilled -> the real historical wall).
// Wave = 16-ROW slice: A-frags direct global->reg, depth-2 prefetch; W1
// (L2-resident) double-buffered in LDS; counted vmcnt(4) per step.
// ---------------------------------------------------------------------------
__global__ __launch_bounds__(512, 2) void k1_gemm1(
    const float* __restrict__ x, const unsigned char* __restrict__ w1bf,
    const float* __restrict__ b1, unsigned char* __restrict__ h1bf) {
  __shared__ unsigned char lds[32768];    // W dbuf 2x16KB; epilogue: h1 image 32KB
  const int tid = threadIdx.x, lane = tid & 63, w = tid >> 6;
  const int l15 = lane & 15, l4 = lane >> 4;

  float b1v[8];
#pragma unroll
  for (int nt = 0; nt < 8; ++nt) {
    int col = nt * 16 + l15;
    b1v[nt] = b1[col < 120 ? col : 119];
  }
  __builtin_amdgcn_sched_barrier(0);

  const float* xbase = x + ((long)blockIdx.x * 128 + w * 16 + l15) * 1024 + l4 * 8;
  const unsigned char* wsrc = w1bf + w * 2048 + lane * 16;

  floatx4 acc[8];
#pragma unroll
  for (int i = 0; i < 8; ++i) acc[i] = floatx4{0.f, 0.f, 0.f, 0.f};

  float4 p[2][4];
  // ---- prologue: W(0) gloads, then x(0)->p[0], x(1)->p[1]
  gload16(wsrc, lds + w * 2048);
  gload16(wsrc + 1024, lds + w * 2048 + 1024);
  __builtin_amdgcn_sched_barrier(0);
#pragma unroll
  for (int ss = 0; ss < 2; ++ss) {
    p[0][ss * 2]     = *(const float4*)(xbase + ss * 32);
    p[0][ss * 2 + 1] = *(const float4*)(xbase + ss * 32 + 4);
  }
#pragma unroll
  for (int ss = 0; ss < 2; ++ss) {
    p[1][ss * 2]     = *(const float4*)(xbase + 64 + ss * 32);
    p[1][ss * 2 + 1] = *(const float4*)(xbase + 64 + ss * 32 + 4);
  }
  __builtin_amdgcn_sched_barrier(0);
  asm volatile("s_waitcnt vmcnt(8)" ::: "memory");   // drain b1v + W(0); x stays in flight
  __builtin_amdgcn_s_barrier();

#pragma unroll
  for (int t = 0; t < 16; ++t) {
    const int cur = t & 1;
    short8 afr[2];
#pragma unroll
    for (int ss = 0; ss < 2; ++ss) {
      float4 a0 = p[cur][ss * 2], a1 = p[cur][ss * 2 + 1];
      union { unsigned u[4]; short8 s; } tmp;
      tmp.u[0] = cvtpk(a0.x, a0.y);
      tmp.u[1] = cvtpk(a0.z, a0.w);
      tmp.u[2] = cvtpk(a1.x, a1.y);
      tmp.u[3] = cvtpk(a1.z, a1.w);
      afr[ss] = tmp.s;
    }
    __builtin_amdgcn_sched_barrier(0);
    if (t < 15) {
      gload16(wsrc + (t + 1) * 16384, lds + (cur ^ 1) * 16384 + w * 2048);
      gload16(wsrc + (t + 1) * 16384 + 1024, lds + (cur ^ 1) * 16384 + w * 2048 + 1024);
    }
    __builtin_amdgcn_sched_barrier(0);
    if (t < 14) {
#pragma unroll
      for (int ss = 0; ss < 2; ++ss) {
        p[cur][ss * 2]     = *(const float4*)(xbase + (t + 2) * 64 + ss * 32);
        p[cur][ss * 2 + 1] = *(const float4*)(xbase + (t + 2) * 64 + ss * 32 + 4);
      }
    }
    __builtin_amdgcn_sched_barrier(0);
    const unsigned char* Wc = lds + cur * 16384;
#pragma unroll
    for (int ss = 0; ss < 2; ++ss)
#pragma unroll
      for (int nt = 0; nt < 8; ++nt) {
        int n = nt * 16 + l15;
        short8 b = *(const short8*)(Wc + n * 128 + ((ss * 64 + l4 * 16) ^ ((n & 7) << 4)));
        acc[nt] = __builtin_amdgcn_mfma_f32_16x16x32_bf16(afr[ss], b, acc[nt], 0, 0, 0);
      }
    if (t < 14)       asm volatile("s_waitcnt vmcnt(4) lgkmcnt(0)" ::: "memory");
    else if (t == 14) asm volatile("s_waitcnt vmcnt(0) lgkmcnt(0)" ::: "memory");
    else              asm volatile("s_waitcnt lgkmcnt(0)" ::: "memory");
    __builtin_amdgcn_s_barrier();
  }

  // epilogue: bias+relu, pack 8 cols -> k-permuted swizzled image, b128 writes
#pragma unroll
  for (int r = 0; r < 4; ++r) {
    int row = w * 16 + l4 * 4 + r;
    float v[8];
#pragma unroll
    for (int nt = 0; nt < 8; ++nt) {
      float t0 = acc[nt][r] + b1v[nt];
      v[nt] = t0 > 0.f ? t0 : 0.f;
    }
    if (l15 >= 8) v[7] = 0.f;                 // cols 120..127 -> 0
    union { unsigned u[4]; short8 s; } tmp;
    tmp.u[0] = cvtpk(v[0], v[1]);
    tmp.u[1] = cvtpk(v[2], v[3]);
    tmp.u[2] = cvtpk(v[4], v[5]);
    tmp.u[3] = cvtpk(v[6], v[7]);
    *(short8*)(lds + row * 256 + ((l15 * 16) ^ ((row & 7) << 4))) = tmp.s;
  }
  __syncthreads();
  {
    const unsigned char* s = lds + tid * 64;
    unsigned char* d = h1bf + (long)blockIdx.x * 32768 + tid * 64;
    *(float4*)(d)      = *(const float4*)(s);
    *(float4*)(d + 16) = *(const float4*)(s + 16);
    *(float4*)(d + 32) = *(const float4*)(s + 32);
    *(float4*)(d + 48) = *(const float4*)(s + 48);
  }
}

// ---------------------------------------------------------------------------
// K2: fused GEMM2 -> LN -> GEMM3 (heads) -> CE tail. R6 structure,
// launch_bounds(512, 2): 128-reg cap fits acc[4][4] (64 AGPR) + ~50 VGPR
// spill-free; LDS 76800 -> 2 blocks/CU.
// ---------------------------------------------------------------------------
__global__ __launch_bounds__(512, 2) void k2_fused(
    const unsigned char* __restrict__ h1bf, const unsigned char* __restrict__ w2f,
    const unsigned char* __restrict__ gbf, const float* __restrict__ cst,
    const float* __restrict__ b2, const int* __restrict__ labels,
    const int* __restrict__ domain, float* __restrict__ out,
    float* __restrict__ partials) {
  extern __shared__ unsigned char lds[];
  unsigned char* h1s = lds;                  // [0,16384)
  unsigned char* h2s = lds;                  // phase B: [0,65536)
  float* stats = (float*)(lds + 65536);      // [64][20]
  float* musig = (float*)(lds + 70656);      // [64][2]
  float* Af    = (float*)(lds + 71168);      // [64][20]

  const int tid = threadIdx.x, lane = tid & 63, w = tid >> 6;
  const int l15 = lane & 15, l4 = lane >> 4;
  const long row0 = (long)blockIdx.x * 64;
  const int n0 = w * 64;

  // ---- stage h1 tile (16 KB): half of k1-block (blockIdx>>1)'s 32KB image
  {
    const unsigned char* hs = h1bf + ((long)(blockIdx.x >> 1)) * 32768 +
                              (blockIdx.x & 1) * 16384 + w * 2048 + lane * 16;
    gload16(hs, h1s + w * 2048);
    gload16(hs + 1024, h1s + w * 2048 + 1024);
  }
  float b2v[4];
#pragma unroll
  for (int nt = 0; nt < 4; ++nt) b2v[nt] = b2[n0 + nt * 16 + l15];
  __syncthreads();

  // ---- GEMM2: 64 rows x 64 cols per wave, K=128 (k-permuted; W2 image matches)
  floatx4 acc[4][4];
#pragma unroll
  for (int i = 0; i < 4; ++i)
#pragma unroll
    for (int j = 0; j < 4; ++j) acc[i][j] = floatx4{0.f, 0.f, 0.f, 0.f};
#pragma unroll
  for (int ks = 0; ks < 4; ++ks) {
    short8 a[4], b[4];
#pragma unroll
    for (int nt = 0; nt < 4; ++nt)
      b[nt] = *(const short8*)(w2f + (((w * 4 + ks) * 4 + nt) * 64 + lane) * 16);
#pragma unroll
    for (int mt = 0; mt < 4; ++mt) {
      int r = mt * 16 + l15;
      a[mt] = *(const short8*)(h1s + r * 256 + ((ks * 64 + l4 * 16) ^ ((r & 7) << 4)));
    }
#pragma unroll
    for (int mt = 0; mt < 4; ++mt)
#pragma unroll
      for (int nt = 0; nt < 4; ++nt)
        acc[mt][nt] = __builtin_amdgcn_mfma_f32_16x16x32_bf16(a[mt], b[nt], acc[mt][nt], 0, 0, 0);
  }

  // ---- bias+relu in regs; LN stats partials (l15-group reduce)
#pragma unroll
  for (int mt = 0; mt < 4; ++mt)
#pragma unroll
    for (int nt = 0; nt < 4; ++nt)
#pragma unroll
      for (int r = 0; r < 4; ++r) {
        float v = acc[mt][nt][r] + b2v[nt];
        acc[mt][nt][r] = v > 0.f ? v : 0.f;
      }
#pragma unroll
  for (int mt = 0; mt < 4; ++mt)
#pragma unroll
    for (int r = 0; r < 4; ++r) {
      float s = 0.f, q2 = 0.f;
#pragma unroll
      for (int nt = 0; nt < 4; ++nt) { float v = acc[mt][nt][r]; s += v; q2 += v * v; }
#pragma unroll
      for (int o = 1; o <= 8; o <<= 1) { s += __shfl_xor(s, o); q2 += __shfl_xor(q2, o); }
      if (l15 == 0) {
        int row = mt * 16 + l4 * 4 + r;
        stats[row * 20 + w * 2] = s;
        stats[row * 20 + w * 2 + 1] = q2;
      }
    }
  __syncthreads();

  if (tid < 64) {
    float S = 0.f, Q = 0.f;
#pragma unroll
    for (int j = 0; j < 8; ++j) { S += stats[tid * 20 + j * 2]; Q += stats[tid * 20 + j * 2 + 1]; }
    float mu = S * (1.f / 512.f);
    float var = Q * (1.f / 512.f) - mu * mu;
    musig[tid * 2] = mu;
    musig[tid * 2 + 1] = rsqrtf(var + 1e-5f);
  }
  __syncthreads();

  // ---- normalized h2 -> packed bf16 (k-permuted, swizzled): 16 x ds_write_b64
#pragma unroll
  for (int mt = 0; mt < 4; ++mt)
#pragma unroll
    for (int r = 0; r < 4; ++r) {
      int row = mt * 16 + l4 * 4 + r;
      float mu = musig[row * 2], rs = musig[row * 2 + 1];
      uint2 qq;
      qq.x = cvtpk((acc[mt][0][r] - mu) * rs, (acc[mt][1][r] - mu) * rs);
      qq.y = cvtpk((acc[mt][2][r] - mu) * rs, (acc[mt][3][r] - mu) * rs);
      *(uint2*)(h2s + row * 1024 + ((w * 128 + l15 * 8) ^ ((row & 7) << 4))) = qq;
    }
  __syncthreads();

  // ---- GEMM3: A[64][10] = h2n @ G^T ; waves 0..3, K=512 (k-permuted G image)
  if (w < 4) {
    floatx4 a3 = floatx4{0.f, 0.f, 0.f, 0.f};
    int row = w * 16 + l15;
#pragma unroll
    for (int t = 0; t < 16; ++t) {
      short8 aa = *(const short8*)(h2s + row * 1024 + ((t * 64 + l4 * 16) ^ ((row & 7) << 4)));
      short8 bb = *(const short8*)(gbf + t * 1024 + lane * 16);
      a3 = __builtin_amdgcn_mfma_f32_16x16x32_bf16(aa, bb, a3, 0, 0, 0);
    }
#pragma unroll
    for (int reg = 0; reg < 4; ++reg) {
      int orow = w * 16 + l4 * 4 + reg;
      if (l15 < 10) Af[orow * 20 + l15] = a3[reg];
    }
  }
  __syncthreads();

  // ---- tail: per-row logits, CE, partial sums (wave 0)
  if (tid < 64) {
    long grow = row0 + tid;
    float pd[10];
#pragma unroll
    for (int q = 0; q < 10; ++q) pd[q] = Af[tid * 20 + q] + cst[q];
    int lab = labels[grow], dm = domain[grow];
    float cw0 = cst[16];
    float ls0 = cw0 * pd[0], ls1 = cw0 * pd[1];
#pragma unroll
    for (int kk = 1; kk < 5; ++kk) {
      float c = cst[32 + dm * 4 + kk - 1];
      ls0 += c * pd[kk * 2];
      ls1 += c * pd[kk * 2 + 1];
    }
    float lc0 = pd[0], lc1 = pd[1];
    *(float2*)(out + 1 + grow * 2) = float2{lc0, lc1};
    float m1 = fmaxf(lc0, lc1), n1 = fminf(lc0, lc1);
    float lse1 = m1 + logf(1.f + expf(n1 - m1));
    float nllc = lse1 - (lab ? lc1 : lc0);
    float m2 = fmaxf(ls0, ls1), n2 = fminf(ls0, ls1);
    float lse2 = m2 + logf(1.f + expf(n2 - m2));
    float nlls = lse2 - (lab ? ls1 : ls0);
    float wl = lab ? 0.9f : 0.1f;
    float wsum = wl, scom = wl * nllc, sspec = wl * nlls;
#pragma unroll
    for (int o = 32; o >= 1; o >>= 1) {
      wsum += __shfl_xor(wsum, o);
      scom += __shfl_xor(scom, o);
      sspec += __shfl_xor(sspec, o);
    }
    if (tid == 0) {
      partials[(long)blockIdx.x * 4] = wsum;
      partials[(long)blockIdx.x * 4 + 1] = scom;
      partials[(long)blockIdx.x * 4 + 2] = sspec;
    }
  }
}

// ---------------------------------------------------------------------------
// K3: deterministic final reduce + orth loss (exact f32) + scalars.
// ---------------------------------------------------------------------------
__global__ __launch_bounds__(256) void k3_finalize(
    const float* __restrict__ partials, const float* __restrict__ sms,
    float* __restrict__ out) {
  __shared__ float wsums[4][3];
  __shared__ float ow[4];
  const int tid = threadIdx.x;
  const int lane = tid & 63, wid = tid >> 6;
  float sw = 0.f, sc = 0.f, ss = 0.f;
  for (int i = tid; i < 1024; i += 256) {
    sw += partials[i * 4];
    sc += partials[i * 4 + 1];
    ss += partials[i * 4 + 2];
  }
#pragma unroll
  for (int o = 32; o >= 1; o >>= 1) {
    sw += __shfl_xor(sw, o);
    sc += __shfl_xor(sc, o);
    ss += __shfl_xor(ss, o);
  }
  if (lane == 0) { wsums[wid][0] = sw; wsums[wid][1] = sc; wsums[wid][2] = ss; }

  float osum = 0.f;
  for (int p = wid; p < 50; p += 4) {
    int c = p / 25, kk = (p / 5) % 5, j = p % 5;
    float acc = 0.f;
#pragma unroll
    for (int hh = 0; hh < 8; ++hh) {
      int h = lane + 64 * hh;
      acc += sms[kk * 1024 + h * 2 + c] * sms[j * 1024 + h * 2 + c];
    }
#pragma unroll
    for (int o = 32; o >= 1; o >>= 1) acc += __shfl_xor(acc, o);
    float d = acc - ((kk == j) ? 1.f : 0.f);
    osum += d * d;
  }
  if (lane == 0) ow[wid] = osum;
  __syncthreads();
  if (tid == 0) {
    float SW = 0.f, SC = 0.f, SS = 0.f, OS = 0.f;
    for (int w = 0; w < 4; ++w) {
      SW += wsums[w][0]; SC += wsums[w][1]; SS += wsums[w][2]; OS += ow[w];
    }
    float orth = OS * (1.f / 50.f);
    float cls = SC / SW;
    float spec = SS / SW;
    out[0] = cls + spec + orth;
    out[131073] = cls;
    out[131074] = spec;
    out[131075] = orth;
  }
}

extern "C" void kernel_launch(void* const* d_in, const int* in_sizes, int n_in,
                              void* d_out, int out_size, void* d_ws, size_t ws_size,
                              hipStream_t stream) {
  const float* x      = (const float*)d_in[0];
  const int* labels   = (const int*)d_in[1];
  const int* domain   = (const int*)d_in[2];
  const float* fc1_w  = (const float*)d_in[3];
  const float* fc1_b  = (const float*)d_in[4];
  const float* fc2_w  = (const float*)d_in[5];
  const float* fc2_b  = (const float*)d_in[6];
  const float* ln_g   = (const float*)d_in[7];
  const float* ln_b   = (const float*)d_in[8];
  const float* sms    = (const float*)d_in[9];
  const float* sm_b   = (const float*)d_in[10];
  const float* embs   = (const float*)d_in[11];
  const float* cs_wt  = (const float*)d_in[12];
  float* out = (float*)d_out;
  unsigned char* ws = (unsigned char*)d_ws;

  (void)hipFuncSetAttribute((const void*)k2_fused,
                            hipFuncAttributeMaxDynamicSharedMemorySize, 76800);

  hipLaunchKernelGGL(k0_prep, dim3(42), dim3(256), 0, stream,
                     fc1_w, fc2_w, ln_g, ln_b, sms, sm_b, embs, cs_wt, ws);
  hipLaunchKernelGGL(k1_gemm1, dim3(BTOT / 128), dim3(512), 0, stream,
                     x, ws + WS_W1BF, fc1_b, ws + WS_H1BF);
  hipLaunchKernelGGL(k2_fused, dim3(BTOT / 64), dim3(512), 76800, stream,
                     ws + WS_H1BF, ws + WS_W2BF, ws + WS_GBF,
                     (const float*)(ws + WS_CONST), fc2_b,
                     labels, domain, out, (float*)(ws + WS_PART));
  hipLaunchKernelGGL(k3_finalize, dim3(1), dim3(256), 0, stream,
                     (const float*)(ws + WS_PART), sms, out);
}